// Round 10
// baseline (1282.654 us; speedup 1.0000x reference)
//
#include <hip/hip_runtime.h>
#include <hip/hip_bf16.h>
#include <stdint.h>

#define LOG2E 1.44269504088896340736f
#define LN2   0.69314718055994530942f
#define GG 8

typedef __attribute__((ext_vector_type(4))) float f32x4;
typedef __attribute__((ext_vector_type(4))) int   i32x4;
typedef __attribute__((ext_vector_type(8))) int   i32x8;
typedef __attribute__((ext_vector_type(2))) uint  u32x2;

static constexpr int B = 128, S = 512, T = 256;
static constexpr int ROW = 68;   // dwords per batch row in LDS staging (64 + 4 pad)

static __device__ __forceinline__ uint pack_bf16x2(float a, float b) {
    __hip_bfloat162 h = __float22bfloat162_rn(make_float2(a, b));
    union { __hip_bfloat162 h; uint u; } cv; cv.h = h;
    return cv.u;
}
static __device__ __forceinline__ float bf2f(uint u) {
    return __uint_as_float(u << 16);
}

// ---------------- prep: Et8[j][i] = fp8_e4m3( exp(trans[i][j]) ) ----------------
__global__ void prep_Et8(const float* __restrict__ trans, uint* __restrict__ Et8) {
    int j  = blockIdx.x;        // 256
    int d  = threadIdx.x;       // 64
    int i0 = d * 4;
    float e0 = exp2f(trans[(i0 + 0) * T + j] * LOG2E);
    float e1 = exp2f(trans[(i0 + 1) * T + j] * LOG2E);
    float e2 = exp2f(trans[(i0 + 2) * T + j] * LOG2E);
    float e3 = exp2f(trans[(i0 + 3) * T + j] * LOG2E);
    uint w = __builtin_amdgcn_cvt_pk_fp8_f32(e0, e1, 0, false);
    w      = __builtin_amdgcn_cvt_pk_fp8_f32(e2, e3, w, true);
    Et8[j * 64 + d] = w;
}

// ---------------- prep: emx = bf16( exp(em) ) ----------------
__global__ void prep_emx(const float* __restrict__ em, ushort* __restrict__ emx) {
    size_t i4 = ((size_t)blockIdx.x * blockDim.x + threadIdx.x) * 4;
    f32x4 e = *reinterpret_cast<const f32x4*>(&em[i4]);
    uint2 w;
    w.x = pack_bf16x2(exp2f(e[0] * LOG2E), exp2f(e[1] * LOG2E));
    w.y = pack_bf16x2(exp2f(e[2] * LOG2E), exp2f(e[3] * LOG2E));
    *reinterpret_cast<uint2*>(&emx[i4]) = w;
}

// prefetch macro: un-sinkable volatile asm global loads (SGPR base = uniform
// s-dependent part, VGPR offset = per-lane batch part, imm = tile offset).
#define EMLD(arr, i, OFF) \
    asm volatile("global_load_dwordx2 %0, %1, %2 offset:" OFF \
                 : "=v"(arr[i]) : "v"(vo_em), "s"(sb_em));

// ---------------- main scan: ONE WAVE per chain, zero barriers ----------------
// 16 blocks x 64 threads; block = (scan, batch-group of 16). Each wave holds
// all 256 states: A-frags 16 m-tiles x 2 kt (fp8, 256 VGPRs, step-invariant),
// 32x mfma_scale_16x16x128 per step. C->B transform = in-wave LDS round-trip
// (no __syncthreads anywhere). Per-step predictive renorm 2^-(kap+G) as R9.
// em/mask prefetched one step ahead via volatile-asm loads, consumed after a
// volatile s_waitcnt-vmcnt(0) pin (loads are ~1 MFMA-block old -> wait free).
// Both scans instruction-identical when mask==1 -> bitwise-identical ->
// partition - score == 0 exactly.
template<bool PRE>
__launch_bounds__(64, 1)
__global__ void crf_scan(const float* __restrict__ em,      // [B][S][T] fp32
                         const ushort* __restrict__ emx,    // [B][S][T] bf16 exp(em)
                         const int* __restrict__ mask,      // [B][S] int32
                         const float* __restrict__ startt,  // [T]
                         const float* __restrict__ endt,    // [T]
                         const uint* __restrict__ Et8,      // [T][64] fp8 rows
                         float* __restrict__ res)           // [2][B]
{
    const int lane = threadIdx.x;
    const int q    = lane >> 4;         // quad 0..3
    const int l    = lane & 15;         // local batch / A-row within m-tile
    const int scan = blockIdx.x & 1;
    const int bg   = blockIdx.x >> 1;   // 0..7
    const int b    = bg * 16 + l;

    __shared__ __align__(16) uint Al[16][ROW];   // alpha fp8 staging (in-wave only)

    // ---- A fragments: row j = 16*mt + l, k-bytes 128kt+32q..+31
    i32x8 Afr[16][2];
    #pragma unroll
    for (int mt = 0; mt < 16; ++mt) {
        const uint* rp = &Et8[(16 * mt + l) * 64];
        #pragma unroll
        for (int kt = 0; kt < 2; ++kt) {
            i32x4 lo = *reinterpret_cast<const i32x4*>(rp + kt * 32 + q * 8);
            i32x4 hi = *reinterpret_cast<const i32x4*>(rp + kt * 32 + q * 8 + 4);
            Afr[mt][kt] = i32x8{lo[0], lo[1], lo[2], lo[3], hi[0], hi[1], hi[2], hi[3]};
        }
    }

    const float* emrow = em + (size_t)b * S * T;
    const int*   mrow  = mask + (size_t)b * S;
    const uint   vo_em = (uint)b * (uint)(S * T * 2) + (uint)(q * 8);
    const uint   vo_mk = (uint)b * (uint)(S * 4);

    int   ls  = 0;
    float gmx;            // per-lane copy of batch-l stored-alpha max
    uint  dw[16];         // stored alpha (fp8), C-dword layout: j = 16t+4q+r

    // ---- init: alpha0 = exp(start + em[:,0]), normalized to max in [1,2)
    {
        float v0[16][4]; float mx = 0.0f;
        #pragma unroll
        for (int t = 0; t < 16; ++t) {
            int j0 = 16 * t + 4 * q;
            f32x4 e4 = *reinterpret_cast<const f32x4*>(&emrow[j0]);
            f32x4 s4 = *reinterpret_cast<const f32x4*>(&startt[j0]);
            #pragma unroll
            for (int r = 0; r < 4; ++r) {
                v0[t][r] = exp2f((e4[r] + s4[r]) * LOG2E);
                mx = fmaxf(mx, v0[t][r]);
            }
        }
        mx = fmaxf(mx, __shfl_xor(mx, 16));
        mx = fmaxf(mx, __shfl_xor(mx, 32));
        int e = (int)((__float_as_uint(mx) >> 23) & 255u) - 127;
        float sc = __uint_as_float((uint)(127 - e) << 23);   // exact 2^-e
        ls = e;
        #pragma unroll
        for (int t = 0; t < 16; ++t) {
            uint w = __builtin_amdgcn_cvt_pk_fp8_f32(v0[t][0] * sc, v0[t][1] * sc, 0, false);
            w      = __builtin_amdgcn_cvt_pk_fp8_f32(v0[t][2] * sc, v0[t][3] * sc, w, true);
            dw[t] = w;
            Al[l][4 * t + q] = w;
        }
        gmx = mx * sc;
    }

    u32x2 exA[16], exB[16]; int mkA = 1, mkB = 1;

    auto prefetch = [&](u32x2 (&nxt)[16], int& mkn, int sp) {
        if constexpr (PRE) {
            uint64_t sb_em = (uint64_t)(uintptr_t)emx  + (uint64_t)sp * (T * 2);
            uint64_t sb_mk = (uint64_t)(uintptr_t)mask + (uint64_t)sp * 4;
            EMLD(nxt, 0, "0")    EMLD(nxt, 1, "32")   EMLD(nxt, 2, "64")   EMLD(nxt, 3, "96")
            EMLD(nxt, 4, "128")  EMLD(nxt, 5, "160")  EMLD(nxt, 6, "192")  EMLD(nxt, 7, "224")
            EMLD(nxt, 8, "256")  EMLD(nxt, 9, "288")  EMLD(nxt, 10, "320") EMLD(nxt, 11, "352")
            EMLD(nxt, 12, "384") EMLD(nxt, 13, "416") EMLD(nxt, 14, "448") EMLD(nxt, 15, "480")
            asm volatile("global_load_dword %0, %1, %2"
                         : "=v"(mkn) : "v"(vo_mk), "s"(sb_mk));
        }
    };

    auto step = [&](u32x2 (&cur)[16], int& mkc, u32x2 (&nxt)[16], int& mkn, int s) {
        const int sp = (s + 1 < S) ? s + 1 : S - 1;
        prefetch(nxt, mkn, sp);

        // B fragments from LDS (in-wave round-trip, no barrier)
        i32x8 Bf[2];
        #pragma unroll
        for (int kt = 0; kt < 2; ++kt) {
            const uint* rp = &Al[l][kt * 32 + q * 8];
            i32x4 lo = *reinterpret_cast<const i32x4*>(rp);
            i32x4 hi = *reinterpret_cast<const i32x4*>(rp + 4);
            Bf[kt] = i32x8{lo[0], lo[1], lo[2], lo[3], hi[0], hi[1], hi[2], hi[3]};
        }

        // MFMA: 32 x mfma_scale 16x16x128 (16 independent acc chains, depth 2)
        f32x4 acc[16];
        #pragma unroll
        for (int mt = 0; mt < 16; ++mt) acc[mt] = f32x4{0, 0, 0, 0};
        #pragma unroll
        for (int kt = 0; kt < 2; ++kt) {
            #pragma unroll
            for (int mt = 0; mt < 16; ++mt)
                acc[mt] = __builtin_amdgcn_mfma_scale_f32_16x16x128_f8f6f4(
                    Afr[mt][kt], Bf[kt], acc[mt], 0, 0, 0, 0x7F, 0, 0x7F);
        }

        // consume prefetched em/mask only after pinning through a waitcnt:
        // loads are a full MFMA block old -> wait is ~free, and the pin stops
        // the compiler from sinking/rematerializing the loads at use sites.
        if constexpr (PRE) {
            asm volatile("s_waitcnt vmcnt(0)"
                         : "+v"(cur[0]), "+v"(cur[1]), "+v"(cur[2]), "+v"(cur[3]),
                           "+v"(cur[4]), "+v"(cur[5]), "+v"(cur[6]), "+v"(cur[7]),
                           "+v"(cur[8]), "+v"(cur[9]), "+v"(cur[10]), "+v"(cur[11]),
                           "+v"(cur[12]), "+v"(cur[13]), "+v"(cur[14]), "+v"(cur[15]),
                           "+v"(mkc));
        }
        const int mk = scan ? (PRE ? mkc : mrow[s]) : 1;

        int   kap  = (int)((__float_as_uint(gmx) >> 23) & 255u) - 127;
        float pend = __uint_as_float((uint)(127 - (kap + GG)) << 23);

        float lmx = 0.0f;
        #pragma unroll
        for (int t = 0; t < 16; ++t) {
            float x0, x1, x2, x3;
            if constexpr (PRE) {
                x0 = bf2f(cur[t].x & 0xFFFFu); x1 = bf2f(cur[t].x >> 16);
                x2 = bf2f(cur[t].y & 0xFFFFu); x3 = bf2f(cur[t].y >> 16);
            } else {
                int j0 = 16 * t + 4 * q;
                f32x4 e4 = *reinterpret_cast<const f32x4*>(&emrow[(size_t)s * T + j0]);
                x0 = exp2f(e4[0] * LOG2E); x1 = exp2f(e4[1] * LOG2E);
                x2 = exp2f(e4[2] * LOG2E); x3 = exp2f(e4[3] * LOG2E);
            }
            float v0 = fminf(acc[t][0] * x0 * pend, 448.0f);
            float v1 = fminf(acc[t][1] * x1 * pend, 448.0f);
            float v2 = fminf(acc[t][2] * x2 * pend, 448.0f);
            float v3 = fminf(acc[t][3] * x3 * pend, 448.0f);
            lmx = fmaxf(fmaxf(lmx, fmaxf(v0, v1)), fmaxf(v2, v3));
            uint w = __builtin_amdgcn_cvt_pk_fp8_f32(v0, v1, 0, false);
            w      = __builtin_amdgcn_cvt_pk_fp8_f32(v2, v3, w, true);
            uint wsel = mk ? w : dw[t];
            dw[t] = wsel;
            Al[l][4 * t + q] = wsel;
        }
        ls += mk ? (kap + GG) : 0;
        float m2 = fmaxf(lmx, __shfl_xor(lmx, 16));
        m2 = fmaxf(m2, __shfl_xor(m2, 32));
        gmx = mk ? m2 : gmx;
    };

    prefetch(exA, mkA, 1);

    #pragma unroll 1
    for (int s = 1; s + 1 < S; s += 2) {
        step(exA, mkA, exB, mkB, s);
        step(exB, mkB, exA, mkA, s + 1);
    }
    step(exA, mkA, exB, mkB, S - 1);
    asm volatile("s_waitcnt vmcnt(0)");   // drain dangling prefetch before endpgm

    // ---- final: res = ls + log2( sum_j alpha[b][j] * exp(end[j]) )
    float part = 0.0f;
    #pragma unroll
    for (int t = 0; t < 16; ++t) {
        int j0 = 16 * t + 4 * q;
        f32x4 e4 = *reinterpret_cast<const f32x4*>(&endt[j0]);
        part += __builtin_amdgcn_cvt_f32_fp8(dw[t], 0) * exp2f(e4[0] * LOG2E);
        part += __builtin_amdgcn_cvt_f32_fp8(dw[t], 1) * exp2f(e4[1] * LOG2E);
        part += __builtin_amdgcn_cvt_f32_fp8(dw[t], 2) * exp2f(e4[2] * LOG2E);
        part += __builtin_amdgcn_cvt_f32_fp8(dw[t], 3) * exp2f(e4[3] * LOG2E);
    }
    part += __shfl_xor(part, 16);
    part += __shfl_xor(part, 32);

    if (q == 0)
        res[scan * B + b] = (float)ls + log2f(part);
}

// ---------------- combine: out[b] = (partition - score) * ln2 ----------------
__global__ void combine(const float* __restrict__ res, float* __restrict__ out) {
    int b = threadIdx.x;  // 128
    out[b] = (res[b] - res[B + b]) * LN2;
}

extern "C" void kernel_launch(void* const* d_in, const int* in_sizes, int n_in,
                              void* d_out, int out_size, void* d_ws, size_t ws_size,
                              hipStream_t stream) {
    (void)in_sizes; (void)n_in; (void)out_size;
    const float* em = (const float*)d_in[0];
    const int*   mk = (const int*)d_in[1];
    const float* st = (const float*)d_in[2];
    const float* en = (const float*)d_in[3];
    const float* tr = (const float*)d_in[4];

    const size_t emx_bytes = (size_t)B * S * T * sizeof(ushort);   // 32 MiB
    const size_t et8_bytes = (size_t)T * 64 * sizeof(uint);        // 64 KiB
    ushort* emx = (ushort*)d_ws;
    uint*   Et8 = (uint*)((char*)d_ws + emx_bytes);
    float*  res = (float*)((char*)d_ws + emx_bytes + et8_bytes);
    const bool pre = ws_size >= emx_bytes + et8_bytes + 4096;

    if (pre) {
        prep_Et8<<<T, 64, 0, stream>>>(tr, Et8);
        prep_emx<<<(B * S * T) / (256 * 4), 256, 0, stream>>>(em, emx);
        crf_scan<true><<<16, 64, 0, stream>>>(em, emx, mk, st, en, Et8, res);
    } else {
        Et8 = (uint*)d_ws;
        res = (float*)((char*)d_ws + et8_bytes);
        prep_Et8<<<T, 64, 0, stream>>>(tr, Et8);
        crf_scan<false><<<16, 64, 0, stream>>>(em, emx, mk, st, en, Et8, res);
    }
    combine<<<1, B, 0, stream>>>(res, (float*)d_out);
}